// Round 15
// baseline (367.589 us; speedup 1.0000x reference)
//
#include <hip/hip_runtime.h>

// LSTM: B=512, T=512, I=128, H=50, O=10, fp32.
// R19: barrier-free single-wave fused kernel; h-exchange via ds_bpermute.
//  R18 account: 1040 cyc/step; wall = 512 x chain for ANY design (batches
//  serial, parallelism maxed) -> only the chain matters. ~700 of 1040 is
//  the h LDS round trip (write+wait+barrier+7xread) — paid by BOTH prior
//  structures (R9 1125, R14 1040). Fix: unit-per-lane single wave; h stays
//  in a register; broadcast = quad_perm pack + 25 pipelined ds_bpermute
//  (uniform idx, loop-invariant, counted lgkm). NOT R10's readlane (that
//  was SALU-hazard-serialized VALU; bpermute is the LDS crossbar).
//  ZERO barriers in the whole kernel (single wave: DS pipe in-order covers
//  wflds->MFMA, xbuf->rec, hf32->fc). MFMA phase: chunk=16 t (52 MFMAs,
//  acc 52 regs), 32 chunks, next chunk's x prefetched under rec phase.
//  Chain est 450-550 vs 1040 -> lstm ~115-155us, e2e ~255-290.

#define BB 512
#define TT 512
#define II 128
#define HH 50
#define GG 200   // 4*H

typedef _Float16 half2v __attribute__((ext_vector_type(2)));
typedef _Float16 half4v __attribute__((ext_vector_type(4)));
typedef _Float16 half8v __attribute__((ext_vector_type(8)));
typedef float float4v __attribute__((ext_vector_type(4)));

#if defined(__has_builtin)
#if __has_builtin(__builtin_amdgcn_fdot2)
#define HAVE_FDOT2 1
#endif
#if __has_builtin(__builtin_amdgcn_rcpf)
#define HAVE_RCPF 1
#endif
#endif

__device__ __forceinline__ float fdot2f(half2v a, half2v b, float c) {
#ifdef HAVE_FDOT2
    return __builtin_amdgcn_fdot2(a, b, c, false);
#else
    return c + (float)a[0] * (float)b[0] + (float)a[1] * (float)b[1];
#endif
}

__device__ __forceinline__ float frcp(float x) {
#ifdef HAVE_RCPF
    return __builtin_amdgcn_rcpf(x);
#else
    return 1.f / x;
#endif
}
__device__ __forceinline__ float fsig(float x) {
    return frcp(1.f + __expf(-x));
}
__device__ __forceinline__ float ftanh(float x) {
    return 2.f * fsig(2.f * x) - 1.f;
}

// ---------------- Kernel 0: prep (once per launch) ----------------
// Gate permutation: gp = unit*4 + gate  <->  orig g = gate*50 + unit.
// wfrags: W_ih rows in PERMUTED order as f16 MFMA B-fragments
//         [nt 13][kc 4][lane 64][j 8]
// whh16:  W_hh rows padded to 56 f16, ORIGINAL order  [g 200][56]
// biasv:  b_ih + b_hh in PERMUTED order               [gp 200]
__global__ __launch_bounds__(256) void prep_kernel(
    const float* __restrict__ W_ih, const float* __restrict__ W_hh,
    const float* __restrict__ b_ih, const float* __restrict__ b_hh,
    _Float16* __restrict__ wfrags, _Float16* __restrict__ whh16,
    float* __restrict__ biasv)
{
    int idx = blockIdx.x * 256 + threadIdx.x;
    if (idx < 3328) {                       // 13*4*64 fragment slots
        int lane = idx & 63, kc = (idx >> 6) & 3, nt = idx >> 8;
        int gp = nt * 16 + (lane & 15);     // permuted gate index
        int k0 = kc * 32 + ((lane >> 4) & 3) * 8;
        half8v v;
        if (gp < GG) {
            int u = gp >> 2, j = gp & 3;
            const float* wr = W_ih + (size_t)(j * HH + u) * II + k0;
            #pragma unroll
            for (int q = 0; q < 8; ++q) v[q] = (_Float16)wr[q];
        } else {
            #pragma unroll
            for (int q = 0; q < 8; ++q) v[q] = (_Float16)0.f;
        }
        *(half8v*)(wfrags + (size_t)idx * 8) = v;
    } else if (idx < 3328 + 2800) {         // 200 rows * 14 quads
        int r = idx - 3328;
        int g = r / 14, j4 = r % 14;
        #pragma unroll
        for (int j = 0; j < 4; ++j) {
            int hidx = j4 * 4 + j;
            whh16[g * 56 + hidx] = (hidx < HH) ? (_Float16)W_hh[g * HH + hidx]
                                               : (_Float16)0.f;
        }
    } else if (idx < 3328 + 2800 + GG) {
        int gp = idx - 6128;
        int u = gp >> 2, j = gp & 3;
        biasv[gp] = b_ih[j * HH + u] + b_hh[j * HH + u];
    }
}

// ---------------- Kernel 1: fused, single-wave, barrier-free ---------------
// Block = batch b, 64 threads (1 wave). 32 chunks of 16 timesteps:
// MFMA phase (52 mfma) fills xbuf[16][200] f16 (bias folded); rec phase
// runs 16 unit-per-lane steps with bpermute h-broadcast. No barriers.
__global__
__attribute__((amdgpu_flat_work_group_size(64, 64)))
__attribute__((amdgpu_waves_per_eu(1, 1)))
void lstm_fused(
    const float* __restrict__ x, const _Float16* __restrict__ wfrags,
    const float* __restrict__ biasv, const _Float16* __restrict__ whh16,
    const float* __restrict__ W_fc, const float* __restrict__ b_fc,
    float* __restrict__ out)
{
    __shared__ __align__(16) _Float16 wflds[3328 * 8];   // 53248 B
    __shared__ __align__(16) _Float16 xbuf[16 * GG];     // 6400 B
    __shared__ float hf32[HH];                           // 200 B -> ~60 KB
    const int l = threadIdx.x;          // 0..63
    const int b = blockIdx.x;
    const int kk = (l < HH) ? l : (HH - 1);   // pad lanes mirror unit 49

    // One-time: stage W_ih fragments to LDS (single wave, 52 b128 copies).
    for (int s = l; s < 3328; s += 64)
        *(float4v*)(wflds + (size_t)s * 8) = *(const float4v*)(wfrags + (size_t)s * 8);

    // Bias for this lane's C-columns (g = nt*16 + (l&15)), loop-invariant.
    float bs[13];
    #pragma unroll
    for (int nt = 0; nt < 13; ++nt) {
        int g = nt * 16 + (l & 15);
        bs[nt] = (g < GG) ? biasv[g] : 0.f;
    }

    // Per-lane W_hh rows (unit kk, 4 gates): 28 x b128 = 112 VGPRs,
    // resident at waves_per_eu(1,1) (proven R7+).
    float4v wr0[7], wr1[7], wr2[7], wr3[7];
    #pragma unroll
    for (int j = 0; j < 7; ++j) {
        wr0[j] = *(const float4v*)(whh16 + (size_t)(kk      ) * 56 + j * 8);
        wr1[j] = *(const float4v*)(whh16 + (size_t)(kk +  50) * 56 + j * 8);
        wr2[j] = *(const float4v*)(whh16 + (size_t)(kk + 100) * 56 + j * 8);
        wr3[j] = *(const float4v*)(whh16 + (size_t)(kk + 150) * 56 + j * 8);
    }

    // MFMA A-source: chunk rows = t 0..15; lane covers row l&15, k-quarter
    // l>>4 (R9/R11-verified fragment mapping).
    const int rq = l >> 4;              // 0..3 (row-quad in C, k-quarter in A)
    const float* xbase = x + ((size_t)b * TT + (l & 15)) * II + rq * 8;

    // Prologue: chunk 0 A-data (8 float4 = 32 VGPRs).
    float4 f0[4], f1[4];
    #pragma unroll
    for (int kc = 0; kc < 4; ++kc) {
        f0[kc] = *(const float4*)(xbase + kc * 32);
        f1[kc] = *(const float4*)(xbase + kc * 32 + 4);
    }

    float c = 0.f, h = 0.f;
    const int colb = l & 15;

    for (int ch = 0; ch < 32; ++ch) {
        // ---------- MFMA phase: xp for t in [ch*16, ch*16+16) ----------
        half8v a[4];
        #pragma unroll
        for (int kc = 0; kc < 4; ++kc) {
            a[kc][0] = (_Float16)f0[kc].x; a[kc][1] = (_Float16)f0[kc].y;
            a[kc][2] = (_Float16)f0[kc].z; a[kc][3] = (_Float16)f0[kc].w;
            a[kc][4] = (_Float16)f1[kc].x; a[kc][5] = (_Float16)f1[kc].y;
            a[kc][6] = (_Float16)f1[kc].z; a[kc][7] = (_Float16)f1[kc].w;
        }
        // Prefetch next chunk's x; consumed after 16 rec steps (~7000 cyc).
        if (ch + 1 < 32) {
            const float* xn = xbase + (size_t)(ch + 1) * 16 * II;
            #pragma unroll
            for (int kc = 0; kc < 4; ++kc) {
                f0[kc] = *(const float4*)(xn + kc * 32);
                f1[kc] = *(const float4*)(xn + kc * 32 + 4);
            }
        }

        float4v acc[13];
        #pragma unroll
        for (int nt = 0; nt < 13; ++nt) acc[nt] = (float4v){0.f, 0.f, 0.f, 0.f};
        #pragma unroll
        for (int kc = 0; kc < 4; ++kc) {
            #pragma unroll
            for (int nt = 0; nt < 13; ++nt) {
                half8v bf = *(const half8v*)(wflds + (size_t)(((nt * 4 + kc) * 64) + l) * 8);
                acc[nt] = __builtin_amdgcn_mfma_f32_16x16x32_f16(a[kc], bf, acc[nt], 0, 0, 0);
            }
        }
        // Write xp+bias to xbuf (C-layout: col=l&15, row=rq*4+reg = t).
        // Single wave: DS in-order; rec reads below see these writes.
        #pragma unroll
        for (int nt = 0; nt < 13; ++nt) {
            int g = nt * 16 + colb;
            if (g < GG) {
                #pragma unroll
                for (int reg = 0; reg < 4; ++reg)
                    xbuf[(rq * 4 + reg) * GG + g] = (_Float16)(acc[nt][reg] + bs[nt]);
            }
        }

        // ---------- REC phase: 16 unit-per-lane steps ----------
        #pragma unroll 4
        for (int t = 0; t < 16; ++t) {
            // xp for this lane's unit: 4 contiguous f16 (permuted layout).
            half4v p = *(const half4v*)(xbuf + t * GG + kk * 4);
            float aI0 = (float)p[0];
            float aF0 = (float)p[1];
            float aG0 = (float)p[2];
            float aO0 = (float)p[3];
            float aI1 = 0.f, aF1 = 0.f, aG1 = 0.f, aO1 = 0.f;

            // h broadcast without LDS round trip: pack pair in even lanes
            // (quad_perm lane^1 swap), then 25 pipelined ds_bpermute with
            // loop-invariant uniform indices.
            _Float16 h16 = (_Float16)h;
            int hi = (int)__builtin_bit_cast(unsigned short, h16);
            int hsw = __builtin_amdgcn_mov_dpp(hi, 0xB1, 0xF, 0xF, true);
            int pk = hi | (hsw << 16);

            #pragma unroll
            for (int m = 0; m < 25; ++m) {
                int sp = __builtin_amdgcn_ds_bpermute(8 * m, pk);  // lane 2m
                half2v hq = __builtin_bit_cast(half2v, sp);
                int j = m >> 2, q = m & 3;
                if (m & 1) {
                    aI1 = fdot2f(hq, ((const half2v*)&wr0[j])[q], aI1);
                    aF1 = fdot2f(hq, ((const half2v*)&wr1[j])[q], aF1);
                    aG1 = fdot2f(hq, ((const half2v*)&wr2[j])[q], aG1);
                    aO1 = fdot2f(hq, ((const half2v*)&wr3[j])[q], aO1);
                } else {
                    aI0 = fdot2f(hq, ((const half2v*)&wr0[j])[q], aI0);
                    aF0 = fdot2f(hq, ((const half2v*)&wr1[j])[q], aF0);
                    aG0 = fdot2f(hq, ((const half2v*)&wr2[j])[q], aG0);
                    aO0 = fdot2f(hq, ((const half2v*)&wr3[j])[q], aO0);
                }
            }
            float ii = fsig(aI0 + aI1);
            float ff = fsig(aF0 + aF1);
            float gg = ftanh(aG0 + aG1);
            float oo = fsig(aO0 + aO1);
            c = ff * c + ii * gg;
            h = oo * ftanh(c);
        }
    }

    // ---------- FC tail (same wave; DS in-order, no barrier) ----------
    if (l < HH) hf32[l] = h;
    if (l < 10) {
        float a = b_fc[l];
        #pragma unroll
        for (int kx = 0; kx < HH; ++kx)
            a += hf32[kx] * W_fc[l * HH + kx];
        out[b * 10 + l] = a;
    }
}

extern "C" void kernel_launch(void* const* d_in, const int* in_sizes, int n_in,
                              void* d_out, int out_size, void* d_ws, size_t ws_size,
                              hipStream_t stream)
{
    const float* x    = (const float*)d_in[0];
    const float* W_ih = (const float*)d_in[1];
    const float* W_hh = (const float*)d_in[2];
    const float* b_ih = (const float*)d_in[3];
    const float* b_hh = (const float*)d_in[4];
    const float* W_fc = (const float*)d_in[5];
    const float* b_fc = (const float*)d_in[6];
    float* out = (float*)d_out;
    char* wsb = (char*)d_ws;

    _Float16* wfrags = (_Float16*)wsb;                      // 53248 B
    _Float16* whh16  = (_Float16*)(wsb + 53248);            // 22400 B
    float*    biasv  = (float*)(wsb + 53248 + 22400);       // 800 B

    prep_kernel<<<25, 256, 0, stream>>>(W_ih, W_hh, b_ih, b_hh,
                                        wfrags, whh16, biasv);
    lstm_fused<<<BB, 64, 0, stream>>>(x, wfrags, biasv, whh16,
                                      W_fc, b_fc, out);
}